// Round 1
// 370.909 us; speedup vs baseline: 1.1137x; 1.1137x over previous
//
#include <hip/hip_runtime.h>
#include <math.h>

#define NTOK 4096

typedef __attribute__((ext_vector_type(8))) short short8;
typedef __attribute__((ext_vector_type(4))) float floatx4;

static __device__ __forceinline__ unsigned short f2bf(float f) {
    unsigned int u = __float_as_uint(f);
    unsigned int r = (u + 0x7fffu + ((u >> 16) & 1u)) >> 16;
    return (unsigned short)r;
}

// async global->LDS, 16B per lane. LDS dest = wave-uniform base + lane*16.
static __device__ __forceinline__ void gload16(const void* g, void* l) {
    __builtin_amdgcn_global_load_lds(
        (const __attribute__((address_space(1))) void*)g,
        (__attribute__((address_space(3))) void*)(unsigned int)(unsigned long long)l,
        16, 0, 0);
}

// 16-lane (DPP row) sum butterfly: all lanes of each 16-lane group end with the
// group sum. VALU-only (v_add_f32_dpp) -- replaces 4 ds_swizzle + 4 adds, so the
// epilogue stops competing with main-loop ds_read_b128 on the LDS pipe.
static __device__ __forceinline__ float row16_sum(float x) {
    x += __int_as_float(__builtin_amdgcn_update_dpp(0, __float_as_int(x), 0xB1, 0xF, 0xF, true));  // quad_perm [1,0,3,2] : xor1
    x += __int_as_float(__builtin_amdgcn_update_dpp(0, __float_as_int(x), 0x4E, 0xF, 0xF, true));  // quad_perm [2,3,0,1] : xor2
    x += __int_as_float(__builtin_amdgcn_update_dpp(0, __float_as_int(x), 0x141, 0xF, 0xF, true)); // row_half_mirror    : xor4-equiv
    x += __int_as_float(__builtin_amdgcn_update_dpp(0, __float_as_int(x), 0x140, 0xF, 0xF, true)); // row_mirror         : xor8-equiv
    return x;
}

#define WAIT_VM12() asm volatile("s_waitcnt vmcnt(12)" ::: "memory")
#define WAIT_VM8()  asm volatile("s_waitcnt vmcnt(8)" ::: "memory")
#define WAIT_VM6()  asm volatile("s_waitcnt vmcnt(6)" ::: "memory")
#define WAIT_VM4()  asm volatile("s_waitcnt vmcnt(4)" ::: "memory")
#define WAIT_VM0()  asm volatile("s_waitcnt vmcnt(0)" ::: "memory")
#define WAIT_LGKM() asm volatile("s_waitcnt lgkmcnt(0)" ::: "memory")

// ce stage: A 256x32 (16KB) + B 128x32 (8KB); 3 stages
#define ASTG 8192   // shorts per A stage
#define BSTG 4096   // shorts per B stage
// hgemm stage: 128x32 A and B (8KB each)
#define STG 4096

// ---------------- merged cvt (6 arrays) + compact (y==6) ----------------
__global__ void cvt_all_k(const float* __restrict__ s0, unsigned short* __restrict__ d0, int e0,
                          const float* __restrict__ s1, unsigned short* __restrict__ d1, int e1,
                          const float* __restrict__ s2, unsigned short* __restrict__ d2, int e2,
                          const float* __restrict__ s3, unsigned short* __restrict__ d3, int e3,
                          const float* __restrict__ s4, unsigned short* __restrict__ d4, int e4,
                          const float* __restrict__ s5, unsigned short* __restrict__ d5, int e5,
                          const int* __restrict__ target,
                          int* __restrict__ idx0, int* __restrict__ lab0, int* __restrict__ n0,
                          int* __restrict__ idx1, int* __restrict__ lab1, int* __restrict__ n1,
                          int* __restrict__ labh) {
    int y = blockIdx.y;
    if (y == 6) {
        int i = blockIdx.x * blockDim.x + threadIdx.x;
        if (i >= NTOK) return;   // NTOK % blockDim == 0 -> wave-uniform exit, ballots safe
        int t = target[i];
        int lane = threadIdx.x & 63;
        unsigned long long below = (1ull << lane) - 1ull;
        bool m0 = (t >= 2000) && (t < 10000);
        bool m1 = (t >= 10000);
        unsigned long long b0 = __ballot(m0);
        unsigned long long b1 = __ballot(m1);
        int ft = t;
        // wave-aggregated compaction: 1 atomic per wave per counter instead of
        // one return-value atomic per token (those serialize at L2).
        if (m0) {
            int ldr = __ffsll((long long)b0) - 1;
            int base = 0;
            if (lane == ldr) base = atomicAdd(n0, __popcll(b0));
            base = __shfl(base, ldr, 64);
            int p = base + __popcll(b0 & below);
            idx0[p] = i; lab0[p] = t - 2000; ft = 2000;
        } else if (m1) {
            int ldr = __ffsll((long long)b1) - 1;
            int base = 0;
            if (lane == ldr) base = atomicAdd(n1, __popcll(b1));
            base = __shfl(base, ldr, 64);
            int p = base + __popcll(b1 & below);
            idx1[p] = i; lab1[p] = t - 10000; ft = 2001;
        }
        labh[i] = ft;
        return;
    }
    const float* s; unsigned short* d; int n;
    switch (y) {
        case 0: s = s0; d = d0; n = e0; break;
        case 1: s = s1; d = d1; n = e1; break;
        case 2: s = s2; d = d2; n = e2; break;
        case 3: s = s3; d = d3; n = e3; break;
        case 4: s = s4; d = d4; n = e4; break;
        default: s = s5; d = d5; n = e5; break;
    }
    int stride = gridDim.x * blockDim.x * 4;
    for (int i = (blockIdx.x * blockDim.x + threadIdx.x) * 4; i < n; i += stride) {
        float4 v = *(const float4*)(s + i);
        ushort4 o;
        o.x = f2bf(v.x); o.y = f2bf(v.y); o.z = f2bf(v.z); o.w = f2bf(v.w);
        *(ushort4*)(d + i) = o;
    }
}

// ---------------- merged gathered h-GEMM, 3-stage, issue-BEFORE-wait (round-4 proven) ----------------
__global__ __launch_bounds__(256)
void hgemm_all_k(const unsigned short* __restrict__ win,
                 const unsigned short* __restrict__ t0w1, unsigned short* __restrict__ h0o,
                 const int* __restrict__ idx0, const int* __restrict__ n0p,
                 const unsigned short* __restrict__ t1w1, unsigned short* __restrict__ h1o,
                 const int* __restrict__ idx1, const int* __restrict__ n1p) {
    __shared__ unsigned short Asm[3 * STG];
    __shared__ unsigned short Bsm[3 * STG];
    __shared__ int sidx[128];
    int bid = blockIdx.x;
    const unsigned short* B; unsigned short* H; const int* idx; int n, P, rb, cb;
    if (bid < 256) { rb = bid >> 3; cb = bid & 7; B = t0w1; H = h0o; idx = idx0; n = *n0p; P = 1024; }
    else { int b = bid - 256; rb = b >> 1; cb = b & 1; B = t1w1; H = h1o; idx = idx1; n = *n1p; P = 256; }
    const int K = 1024, T = 32;
    int row_base = rb * 128;
    if (row_base >= n) return;
    int col_base = cb * 128;
    int t = threadIdx.x;
    int wave = t >> 6, lane = t & 63;
    int wrow = (wave >> 1) * 64, wcol = (wave & 1) * 64;
    int fr = lane & 15, fk = lane >> 4;

    if (t < 128) { int r = row_base + t; sidx[t] = idx[r < n ? r : n - 1]; }
    __syncthreads();   // drains vmcnt: clean slate before manual pipeline (gather needs sidx)

    int sr0 = wave * 32 + (lane >> 2);
    int sr1 = sr0 + 16;
    int c0l = lane & 3;
    int gc0 = c0l ^ ((sr0 >> 1) & 3);
    int gc1 = c0l ^ ((sr1 >> 1) & 3);
    const unsigned short* Ab0 = win + (size_t)sidx[sr0] * K + gc0 * 8;
    const unsigned short* Ab1 = win + (size_t)sidx[sr1] * K + gc1 * 8;
    const unsigned short* Bb0 = B + (size_t)(col_base + sr0) * K + gc0 * 8;
    const unsigned short* Bb1 = B + (size_t)(col_base + sr1) * K + gc1 * 8;

    auto issue = [&](int s, int slot) {
        int koff = s << 5;
        unsigned short* as = Asm + slot * STG + wave * 1024;
        unsigned short* bs = Bsm + slot * STG + wave * 1024;
        gload16(Ab0 + koff, as); gload16(Ab1 + koff, as + 512);
        gload16(Bb0 + koff, bs); gload16(Bb1 + koff, bs + 512);
    };

    int sw = (fk ^ ((fr >> 1) & 3)) * 8;
    int ra[4], rc[4];
#pragma unroll
    for (int i = 0; i < 4; ++i) {
        ra[i] = (wrow + i * 16 + fr) * 32 + sw;
        rc[i] = (wcol + i * 16 + fr) * 32 + sw;
    }

    issue(0, 0); issue(1, 1);
    floatx4 acc[4][4] = {};
    int sc = 0, si = 2;
    for (int j = 0; j < T; ++j) {
        if (j + 2 < T) { issue(j + 2, si); si = (si == 2) ? 0 : si + 1; }
        int rem = T - 1 - j;
        if (rem >= 2) { WAIT_VM8(); }
        else if (rem == 1) { WAIT_VM4(); }
        else { WAIT_VM0(); }
        WAIT_LGKM();
        __builtin_amdgcn_s_barrier();
        const unsigned short* As = Asm + sc * STG;
        const unsigned short* Bs = Bsm + sc * STG;
        sc = (sc == 2) ? 0 : sc + 1;
        short8 af[4], bf[4];
#pragma unroll
        for (int i = 0; i < 4; ++i) af[i] = *(const short8*)&As[ra[i]];
#pragma unroll
        for (int i = 0; i < 4; ++i) bf[i] = *(const short8*)&Bs[rc[i]];
#pragma unroll
        for (int rt = 0; rt < 4; ++rt)
#pragma unroll
            for (int ct = 0; ct < 4; ++ct)
                acc[rt][ct] = __builtin_amdgcn_mfma_f32_16x16x32_bf16(af[rt], bf[ct], acc[rt][ct], 0, 0, 0);
    }
#pragma unroll
    for (int rt = 0; rt < 4; ++rt)
#pragma unroll
        for (int r = 0; r < 4; ++r) {
            int row = row_base + wrow + rt * 16 + fk * 4 + r;
#pragma unroll
            for (int ct = 0; ct < 4; ++ct) {
                int col = col_base + wcol + ct * 16 + fr;
                H[(size_t)row * P + col] = f2bf(acc[rt][ct][r]);
            }
        }
}

// ---------------- CE: 256x128 tiles, one chunk per block, post-loop epilogue ----------------
// 3-stage, issue-BEFORE-wait (round-4 proven ordering: prefetch stays in flight
// across the vmcnt stall -> P ~ L/2 instead of L). 6 loads/wave/stage -> waits 12/6/0.
// slab is loaded via gload16 folded into stage 0 (A addresses are direct, slab is
// epilogue-only) -> no initial syncthreads, no exposed slab latency. It is the
// 7th-oldest vm op at j=0, so WAIT_VM12 covers it with unchanged constants.
// seg1 (bid<5008):    tail1 V=40000 K=256  (16 rb x 313 ch), T=8
// seg0 (5008..6015):  tail0 V=8000  K=1024 (16 rb x 63 ch),  T=32
// segh (6016..6271):  head  V=2002  K=1024 (16 rb x 16 ch),  T=32, +bias
__global__ __launch_bounds__(256, 2)
void ce_all_k(const unsigned short* __restrict__ h1, const unsigned short* __restrict__ t1w2,
              const int* __restrict__ lab1, const int* __restrict__ n1p,
              float* __restrict__ ps1, float* __restrict__ ll1,
              const unsigned short* __restrict__ h0, const unsigned short* __restrict__ t0w2,
              const int* __restrict__ lab0, const int* __restrict__ n0p,
              float* __restrict__ ps0, float* __restrict__ ll0,
              const unsigned short* __restrict__ win, const unsigned short* __restrict__ hw,
              const float* __restrict__ head_b, const int* __restrict__ labh,
              float* __restrict__ psh, float* __restrict__ llh) {
    __shared__ unsigned short Asm[3 * ASTG];
    __shared__ unsigned short Bsm[3 * BSTG];
    __shared__ int slab[256];
    __shared__ float cs[256][2];
    __shared__ float cl[256][2];
    int bid = blockIdx.x;
    const unsigned short* A; const unsigned short* B; const float* bias = nullptr;
    const int* labels; int n, V, kbits, T, rb, ch;
    float* ps; float* ll;
    if (bid < 5008) {
        rb = bid / 313; ch = bid % 313;
        A = h1; B = t1w2; labels = lab1; n = *n1p; V = 40000; kbits = 8; T = 8;
        ps = ps1; ll = ll1;
    } else if (bid < 6016) {
        int b = bid - 5008; rb = b / 63; ch = b % 63;
        A = h0; B = t0w2; labels = lab0; n = *n0p; V = 8000; kbits = 10; T = 32;
        ps = ps0; ll = ll0;
    } else {
        int b = bid - 6016; rb = b >> 4; ch = b & 15;
        A = win; B = hw; labels = labh; n = NTOK; V = 2002; kbits = 10; T = 32;
        ps = psh; ll = llh; bias = head_b;
    }
    int row_base = rb * 256;
    if (row_base >= n) return;
    int colb = ch << 7;
    int Vm1 = V - 1;
    int t = threadIdx.x;
    int wave = t >> 6, lane = t & 63;
    int wrow = (wave >> 1) * 128, wcol = (wave & 1) * 64;
    int fr = lane & 15, fk = lane >> 4;

    // staging: A 256x32 (4 instr/wave, 16-row steps), B 128x32 (2 instr/wave)
    int sra = wave * 64 + (lane >> 2);
    int srb = wave * 32 + (lane >> 2);
    int c0l = lane & 3;
    int gca = c0l ^ ((sra >> 1) & 3);   // +16 row steps preserve (r>>1)&3
    int gcb = c0l ^ ((srb >> 1) & 3);
    const unsigned short* Ap0 = A + (((size_t)(row_base + sra)) << kbits) + gca * 8;
    const unsigned short* Ap1 = A + (((size_t)(row_base + sra + 16)) << kbits) + gca * 8;
    const unsigned short* Ap2 = A + (((size_t)(row_base + sra + 32)) << kbits) + gca * 8;
    const unsigned short* Ap3 = A + (((size_t)(row_base + sra + 48)) << kbits) + gca * 8;
    int br0 = colb + srb;      if (br0 > Vm1) br0 = Vm1;
    int br1 = colb + srb + 16; if (br1 > Vm1) br1 = Vm1;
    const unsigned short* Bp0 = B + (((size_t)br0) << kbits) + gcb * 8;
    const unsigned short* Bp1 = B + (((size_t)br1) << kbits) + gcb * 8;

    auto issue = [&](int s, int slot) {
        int koff = s << 5;
        unsigned short* as = Asm + slot * ASTG + wave * 2048;
        unsigned short* bs = Bsm + slot * BSTG + wave * 1024;
        gload16(Ap0 + koff, as);        gload16(Ap1 + koff, as + 512);
        gload16(Ap2 + koff, as + 1024); gload16(Ap3 + koff, as + 1536);
        gload16(Bp0 + koff, bs);        gload16(Bp1 + koff, bs + 512);
    };

    int sw = (fk ^ ((fr >> 1) & 3)) * 8;
    int ra[8], rc[4];
#pragma unroll
    for (int i = 0; i < 8; ++i) ra[i] = (wrow + i * 16 + fr) * 32 + sw;
#pragma unroll
    for (int i = 0; i < 4; ++i) rc[i] = (wcol + i * 16 + fr) * 32 + sw;

    issue(0, 0);
    // slab: every wave loads the same 256 labels (64 lanes x 16B) to the same
    // LDS dest -- redundant identical writes are benign; 7th vm op of stage 0.
    gload16(labels + row_base + (lane << 2), slab);
    issue(1, 1);
    floatx4 acc[8][4] = {};
    int sc = 0, si = 2;
    for (int j = 0; j < T; ++j) {
        if (j + 2 < T) { issue(j + 2, si); si = (si == 2) ? 0 : si + 1; }
        int rem = T - 1 - j;
        if (rem >= 2) { WAIT_VM12(); }
        else if (rem == 1) { WAIT_VM6(); }
        else { WAIT_VM0(); }
        WAIT_LGKM();
        __builtin_amdgcn_s_barrier();
        const unsigned short* As = Asm + sc * ASTG;
        const unsigned short* Bs = Bsm + sc * BSTG;
        sc = (sc == 2) ? 0 : sc + 1;
        short8 af[8], bf[4];
#pragma unroll
        for (int i = 0; i < 8; ++i) af[i] = *(const short8*)&As[ra[i]];
#pragma unroll
        for (int i = 0; i < 4; ++i) bf[i] = *(const short8*)&Bs[rc[i]];
#pragma unroll
        for (int rt = 0; rt < 8; ++rt)
#pragma unroll
            for (int ct = 0; ct < 4; ++ct)
                acc[rt][ct] = __builtin_amdgcn_mfma_f32_16x16x32_bf16(af[rt], bf[ct], acc[rt][ct], 0, 0, 0);
    }

    // post-loop epilogue: bias + OOB->-inf fold + label capture + per-row sum(exp).
    // |logit| < ~6 (xavier) -> max-free sum(exp) is fp32-safe. OOB columns get
    // bv=-1e30 -> exp underflows to exactly 0 (no per-element cmp/select).
    // 16-lane reduce is DPP (VALU) -- zero DS ops, no LDS-pipe contention.
    float bv[4]; int vc[4];
#pragma unroll
    for (int ct = 0; ct < 4; ++ct) {
        vc[ct] = colb + wcol + ct * 16 + fr;
        bv[ct] = (vc[ct] < V) ? ((bias != nullptr) ? bias[vc[ct]] : 0.f) : -1e30f;
    }
#pragma unroll
    for (int rt = 0; rt < 8; ++rt) {
        int lbase = wrow + rt * 16 + fk * 4;
        int4 labs = *(const int4*)&slab[lbase];   // 4 consecutive rows' labels, one ds_read_b128
#pragma unroll
        for (int r = 0; r < 4; ++r) {
            int lab = ((const int*)&labs)[r];
            float s = 0.f, lv = 0.f;
#pragma unroll
            for (int ct = 0; ct < 4; ++ct) {
                float L = acc[rt][ct][r] + bv[ct];
                lv = (vc[ct] == lab) ? L : lv;
                s += __expf(L);
            }
            s = row16_sum(s);
            lv = row16_sum(lv);   // exact: at most one nonzero contribution
            if (fr == 0) { int lrow = lbase + r; cs[lrow][wave & 1] = s; cl[lrow][wave & 1] = lv; }
        }
    }
    __syncthreads();
    ps[(size_t)ch * NTOK + row_base + t] = cs[t][0] + cs[t][1];
    int lr = slab[t] - colb;
    if (lr >= 0 && lr < 128)
        ll[row_base + t] = cl[t][0] + cl[t][1];
}

// ---------------- merged per-row LSE reduce + NLL sum (3 segments) ----------------
__global__ void reduce_all_k(const float* __restrict__ ps0, const float* __restrict__ ll0,
                             const int* __restrict__ n0p, int nc0,
                             const float* __restrict__ ps1, const float* __restrict__ ll1,
                             const int* __restrict__ n1p, int nc1,
                             const float* __restrict__ psh, const float* __restrict__ llh, int nch,
                             float* __restrict__ loss) {
    int i = blockIdx.x * blockDim.x + threadIdx.x;
    int seg = i >> 12;
    int r = i & 4095;
    const float* ps; const float* ll; int nc, n;
    if (seg == 0)      { ps = ps0; ll = ll0; nc = nc0; n = *n0p; }
    else if (seg == 1) { ps = ps1; ll = ll1; nc = nc1; n = *n1p; }
    else               { ps = psh; ll = llh; nc = nch; n = NTOK; }
    float nll = 0.f;
    if (r < n) {
        float S = 0.f;
        for (int c = 0; c < nc; ++c) S += ps[(size_t)c * NTOK + r];
        nll = logf(S) - ll[r];
    }
    for (int off = 32; off; off >>= 1) nll += __shfl_down(nll, off, 64);
    if ((threadIdx.x & 63) == 0) atomicAdd(loss, nll);
}

__global__ void final_k(const float* __restrict__ loss, float* __restrict__ out) {
    out[0] = loss[0] * (1.0f / 4096.0f);
}

extern "C" void kernel_launch(void* const* d_in, const int* in_sizes, int n_in,
                              void* d_out, int out_size, void* d_ws, size_t ws_size,
                              hipStream_t stream) {
    const float* w_in   = (const float*)d_in[0];
    const int*   target = (const int*)d_in[1];
    const float* head_w = (const float*)d_in[2];
    const float* head_b = (const float*)d_in[3];
    const float* t0w1   = (const float*)d_in[4];
    const float* t0w2   = (const float*)d_in[5];
    const float* t1w1   = (const float*)d_in[6];
    const float* t1w2   = (const float*)d_in[7];
    float* out = (float*)d_out;

    char* wsb = (char*)d_ws;
    size_t o = 0;
    auto alloc = [&](size_t bytes) -> void* {
        void* p = wsb + o;
        o += (bytes + 255) & ~(size_t)255;
        return p;
    };
    float* loss = (float*)alloc(4);
    int* n0 = (int*)alloc(4);
    int* n1 = (int*)alloc(4);
    int* idx0 = (int*)alloc(NTOK * 4);
    int* lab0 = (int*)alloc(NTOK * 4);
    int* idx1 = (int*)alloc(NTOK * 4);
    int* lab1 = (int*)alloc(NTOK * 4);
    int* labh = (int*)alloc(NTOK * 4);

    const int SZ_WIN = NTOK * 1024, SZ_HW = 2002 * 1024, SZ_T0W1 = 1024 * 1024,
              SZ_T0W2 = 8000 * 1024, SZ_T1W1 = 256 * 1024, SZ_T1W2 = 40000 * 256;
    unsigned short* win_bf  = (unsigned short*)alloc((size_t)SZ_WIN * 2);
    unsigned short* hw_bf   = (unsigned short*)alloc((size_t)SZ_HW * 2);
    unsigned short* t0w1_bf = (unsigned short*)alloc((size_t)SZ_T0W1 * 2);
    unsigned short* t0w2_bf = (unsigned short*)alloc((size_t)SZ_T0W2 * 2);
    unsigned short* t1w1_bf = (unsigned short*)alloc((size_t)SZ_T1W1 * 2);
    unsigned short* t1w2_bf = (unsigned short*)alloc((size_t)SZ_T1W2 * 2);
    unsigned short* h0 = (unsigned short*)alloc((size_t)NTOK * 1024 * 2);
    unsigned short* h1 = (unsigned short*)alloc((size_t)NTOK * 256 * 2);

    const int NC0 = 63, NC1 = 313, NCH = 16;   // chunks per segment (per-chunk partials)
    float* ps0 = (float*)alloc((size_t)NC0 * NTOK * 4);
    float* ps1 = (float*)alloc((size_t)NC1 * NTOK * 4);
    float* psh = (float*)alloc((size_t)NCH * NTOK * 4);
    float* ll0 = (float*)alloc(NTOK * 4);
    float* ll1 = (float*)alloc(NTOK * 4);
    float* llh = (float*)alloc(NTOK * 4);

    dim3 blk(256);
    hipMemsetAsync(d_ws, 0, 768, stream);   // zero loss, n0, n1
    cvt_all_k<<<dim3(640, 7), blk, 0, stream>>>(
        w_in, win_bf, SZ_WIN, head_w, hw_bf, SZ_HW, t0w1, t0w1_bf, SZ_T0W1,
        t0w2, t0w2_bf, SZ_T0W2, t1w1, t1w1_bf, SZ_T1W1, t1w2, t1w2_bf, SZ_T1W2,
        target, idx0, lab0, n0, idx1, lab1, n1, labh);

    hgemm_all_k<<<320, blk, 0, stream>>>(win_bf, t0w1_bf, h0, idx0, n0,
                                         t1w1_bf, h1, idx1, n1);

    ce_all_k<<<5008 + 1008 + 256, blk, 0, stream>>>(
        h1, t1w2_bf, lab1, n1, ps1, ll1,
        h0, t0w2_bf, lab0, n0, ps0, ll0,
        win_bf, hw_bf, head_b, labh, psh, llh);

    reduce_all_k<<<3 * NTOK / 256, blk, 0, stream>>>(ps0, ll0, n0, NC0,
                                                     ps1, ll1, n1, NC1,
                                                     psh, llh, NCH, loss);
    final_k<<<1, 1, 0, stream>>>(loss, out);
}

// Round 3
// 291.471 us; speedup vs baseline: 1.4172x; 1.2725x over previous
//
#include <hip/hip_runtime.h>
#include <math.h>

#define NTOK 4096

typedef __attribute__((ext_vector_type(8))) short short8;
typedef __attribute__((ext_vector_type(4))) float floatx4;

static __device__ __forceinline__ unsigned short f2bf(float f) {
    unsigned int u = __float_as_uint(f);
    unsigned int r = (u + 0x7fffu + ((u >> 16) & 1u)) >> 16;
    return (unsigned short)r;
}

static __device__ __forceinline__ float bf2f(unsigned short s) {
    return __uint_as_float((unsigned)s << 16);
}

// async global->LDS, 16B per lane. LDS dest = wave-uniform base + lane*16.
static __device__ __forceinline__ void gload16(const void* g, void* l) {
    __builtin_amdgcn_global_load_lds(
        (const __attribute__((address_space(1))) void*)g,
        (__attribute__((address_space(3))) void*)(unsigned int)(unsigned long long)l,
        16, 0, 0);
}

// 16-lane (DPP row) sum butterfly: all lanes of each 16-lane group end with the
// group sum. VALU-only -- no LDS-pipe contention with main-loop ds_read_b128.
static __device__ __forceinline__ float row16_sum(float x) {
    x += __int_as_float(__builtin_amdgcn_update_dpp(0, __float_as_int(x), 0xB1, 0xF, 0xF, true));  // quad_perm xor1
    x += __int_as_float(__builtin_amdgcn_update_dpp(0, __float_as_int(x), 0x4E, 0xF, 0xF, true));  // quad_perm xor2
    x += __int_as_float(__builtin_amdgcn_update_dpp(0, __float_as_int(x), 0x141, 0xF, 0xF, true)); // row_half_mirror
    x += __int_as_float(__builtin_amdgcn_update_dpp(0, __float_as_int(x), 0x140, 0xF, 0xF, true)); // row_mirror
    return x;
}

#define WAIT_VM12() asm volatile("s_waitcnt vmcnt(12)" ::: "memory")
#define WAIT_VM8()  asm volatile("s_waitcnt vmcnt(8)" ::: "memory")
#define WAIT_VM6()  asm volatile("s_waitcnt vmcnt(6)" ::: "memory")
#define WAIT_VM4()  asm volatile("s_waitcnt vmcnt(4)" ::: "memory")
#define WAIT_VM0()  asm volatile("s_waitcnt vmcnt(0)" ::: "memory")
#define WAIT_LGKM() asm volatile("s_waitcnt lgkmcnt(0)" ::: "memory")

// ce stage: A 256x32 (16KB) + B 128x32 (8KB); 3 stages
#define ASTG 8192   // shorts per A stage
#define BSTG 4096   // shorts per B stage
// hgemm stage: 128x32 A and B (8KB each)
#define STG 4096

// ---------------- prep: compact (blocks 0..15) + cvt of win/t0w1/t1w1 ----------------
// flat-indexed cvt: block allocation proportional to array size (no per-array tail).
__global__ __launch_bounds__(256)
void prep_k(const float* __restrict__ w_in, unsigned short* __restrict__ win_bf,
            const float* __restrict__ t0w1, unsigned short* __restrict__ t0w1_bf,
            const float* __restrict__ t1w1, unsigned short* __restrict__ t1w1_bf,
            const int* __restrict__ target,
            int* __restrict__ idx0, int* __restrict__ lab0, int* __restrict__ n0,
            int* __restrict__ idx1, int* __restrict__ lab1, int* __restrict__ n1,
            int* __restrict__ labh) {
    int bid = blockIdx.x;
    if (bid < 16) {
        int i = bid * 256 + threadIdx.x;   // 4096 threads exactly, wave-uniform
        int t = target[i];
        int lane = threadIdx.x & 63;
        unsigned long long below = (1ull << lane) - 1ull;
        bool m0 = (t >= 2000) && (t < 10000);
        bool m1 = (t >= 10000);
        unsigned long long b0 = __ballot(m0);
        unsigned long long b1 = __ballot(m1);
        int ft = t;
        // wave-aggregated compaction: 1 atomic per wave per counter.
        if (m0) {
            int ldr = __ffsll((long long)b0) - 1;
            int base = 0;
            if (lane == ldr) base = atomicAdd(n0, __popcll(b0));
            base = __shfl(base, ldr, 64);
            int p = base + __popcll(b0 & below);
            idx0[p] = i; lab0[p] = t - 2000; ft = 2000;
        } else if (m1) {
            int ldr = __ffsll((long long)b1) - 1;
            int base = 0;
            if (lane == ldr) base = atomicAdd(n1, __popcll(b1));
            base = __shfl(base, ldr, 64);
            int p = base + __popcll(b1 & below);
            idx1[p] = i; lab1[p] = t - 10000; ft = 2001;
        }
        labh[i] = ft;
        return;
    }
    // cvt: flat float4 index over [w_in | t0w1 | t1w1]
    const int E0 = 4194304, E1 = E0 + 1048576, TOT = E1 + 262144;   // floats
    int gi = (bid - 16) * 256 + threadIdx.x;
    int stride = (gridDim.x - 16) * 256;
    for (int i4 = gi; i4 * 4 < TOT; i4 += stride) {
        int i = i4 * 4;
        const float* s; unsigned short* d; int off;
        if (i < E0)      { s = w_in;  d = win_bf;  off = i; }
        else if (i < E1) { s = t0w1; d = t0w1_bf; off = i - E0; }
        else             { s = t1w1; d = t1w1_bf; off = i - E1; }
        float4 v = *(const float4*)(s + off);
        ushort4 o;
        o.x = f2bf(v.x); o.y = f2bf(v.y); o.z = f2bf(v.z); o.w = f2bf(v.w);
        *(ushort4*)(d + off) = o;
    }
}

// ---------------- merged gathered h-GEMM (blocks 0..319) + cvt of hw/t0w2/t1w2 ----------------
// hgemm only has ~100 active blocks (>60% of CUs idle) -- the cvt blocks fill
// the rest of the machine, overlapping 102MB of pure-BW work with the GEMM.
__global__ __launch_bounds__(256)
void hgemm_cvt_k(const unsigned short* __restrict__ win,
                 const unsigned short* __restrict__ t0w1, unsigned short* __restrict__ h0o,
                 const int* __restrict__ idx0, const int* __restrict__ n0p,
                 const unsigned short* __restrict__ t1w1, unsigned short* __restrict__ h1o,
                 const int* __restrict__ idx1, const int* __restrict__ n1p,
                 const float* __restrict__ head_w, unsigned short* __restrict__ hw_bf,
                 const float* __restrict__ t0w2, unsigned short* __restrict__ t0w2_bf,
                 const float* __restrict__ t1w2, unsigned short* __restrict__ t1w2_bf) {
    __shared__ unsigned short Asm[3 * STG];
    __shared__ unsigned short Bsm[3 * STG];
    __shared__ int sidx[128];
    int bid = blockIdx.x;
    if (bid >= 320) {
        const int E0 = 2050048, E1 = E0 + 8192000, TOT = E1 + 10240000;   // floats
        int gi = (bid - 320) * 256 + threadIdx.x;
        int stride = (gridDim.x - 320) * 256;
        for (int i4 = gi; i4 * 4 < TOT; i4 += stride) {
            int i = i4 * 4;
            const float* s; unsigned short* d; int off;
            if (i < E0)      { s = head_w; d = hw_bf;   off = i; }
            else if (i < E1) { s = t0w2;  d = t0w2_bf; off = i - E0; }
            else             { s = t1w2;  d = t1w2_bf; off = i - E1; }
            float4 v = *(const float4*)(s + off);
            ushort4 o;
            o.x = f2bf(v.x); o.y = f2bf(v.y); o.z = f2bf(v.z); o.w = f2bf(v.w);
            *(ushort4*)(d + off) = o;
        }
        return;
    }
    const unsigned short* B; unsigned short* H; const int* idx; int n, P, rb, cb;
    if (bid < 256) { rb = bid >> 3; cb = bid & 7; B = t0w1; H = h0o; idx = idx0; n = *n0p; P = 1024; }
    else { int b = bid - 256; rb = b >> 1; cb = b & 1; B = t1w1; H = h1o; idx = idx1; n = *n1p; P = 256; }
    const int K = 1024, T = 32;
    int row_base = rb * 128;
    if (row_base >= n) return;
    int col_base = cb * 128;
    int t = threadIdx.x;
    int wave = t >> 6, lane = t & 63;
    int wrow = (wave >> 1) * 64, wcol = (wave & 1) * 64;
    int fr = lane & 15, fk = lane >> 4;

    if (t < 128) { int r = row_base + t; sidx[t] = idx[r < n ? r : n - 1]; }
    __syncthreads();   // drains vmcnt: clean slate before manual pipeline (gather needs sidx)

    int sr0 = wave * 32 + (lane >> 2);
    int sr1 = sr0 + 16;
    int c0l = lane & 3;
    int gc0 = c0l ^ ((sr0 >> 1) & 3);
    int gc1 = c0l ^ ((sr1 >> 1) & 3);
    const unsigned short* Ab0 = win + (size_t)sidx[sr0] * K + gc0 * 8;
    const unsigned short* Ab1 = win + (size_t)sidx[sr1] * K + gc1 * 8;
    const unsigned short* Bb0 = B + (size_t)(col_base + sr0) * K + gc0 * 8;
    const unsigned short* Bb1 = B + (size_t)(col_base + sr1) * K + gc1 * 8;

    auto issue = [&](int s, int slot) {
        int koff = s << 5;
        unsigned short* as = Asm + slot * STG + wave * 1024;
        unsigned short* bs = Bsm + slot * STG + wave * 1024;
        gload16(Ab0 + koff, as); gload16(Ab1 + koff, as + 512);
        gload16(Bb0 + koff, bs); gload16(Bb1 + koff, bs + 512);
    };

    int sw = (fk ^ ((fr >> 1) & 3)) * 8;
    int ra[4], rc[4];
#pragma unroll
    for (int i = 0; i < 4; ++i) {
        ra[i] = (wrow + i * 16 + fr) * 32 + sw;
        rc[i] = (wcol + i * 16 + fr) * 32 + sw;
    }

    issue(0, 0); issue(1, 1);
    floatx4 acc[4][4] = {};
    int sc = 0, si = 2;
    for (int j = 0; j < T; ++j) {
        if (j + 2 < T) { issue(j + 2, si); si = (si == 2) ? 0 : si + 1; }
        int rem = T - 1 - j;
        if (rem >= 2) { WAIT_VM8(); }
        else if (rem == 1) { WAIT_VM4(); }
        else { WAIT_VM0(); }
        WAIT_LGKM();
        __builtin_amdgcn_s_barrier();
        const unsigned short* As = Asm + sc * STG;
        const unsigned short* Bs = Bsm + sc * STG;
        sc = (sc == 2) ? 0 : sc + 1;
        short8 af[4], bf[4];
#pragma unroll
        for (int i = 0; i < 4; ++i) af[i] = *(const short8*)&As[ra[i]];
#pragma unroll
        for (int i = 0; i < 4; ++i) bf[i] = *(const short8*)&Bs[rc[i]];
#pragma unroll
        for (int rt = 0; rt < 4; ++rt)
#pragma unroll
            for (int ct = 0; ct < 4; ++ct)
                acc[rt][ct] = __builtin_amdgcn_mfma_f32_16x16x32_bf16(af[rt], bf[ct], acc[rt][ct], 0, 0, 0);
    }
#pragma unroll
    for (int rt = 0; rt < 4; ++rt)
#pragma unroll
        for (int r = 0; r < 4; ++r) {
            int row = row_base + wrow + rt * 16 + fk * 4 + r;
#pragma unroll
            for (int ct = 0; ct < 4; ++ct) {
                int col = col_base + wcol + ct * 16 + fr;
                H[(size_t)row * P + col] = f2bf(acc[rt][ct][r]);
            }
        }
}

// ---------------- CE: 256x128 tiles, sum(exp) only (label logit moved to reduce) ----------------
// 3-stage, issue-BEFORE-wait. 6 loads/wave/stage -> waits 12/6/0.
// Epilogue per element: fma(exp(acc), ebv, s) -- bias and OOB folded into the
// precomputed multiplier ebv (=exp(bias), or 0 for col>=V). No label compare,
// no second DPP chain, no slab: label logits are recomputed in reduce_all_k
// as a trivial per-token K-dot (5M MACs total).
// seg1 (bid<5008):    tail1 V=40000 K=256  (16 rb x 313 ch), T=8
// seg0 (5008..6015):  tail0 V=8000  K=1024 (16 rb x 63 ch),  T=32
// segh (6016..6271):  head  V=2002  K=1024 (16 rb x 16 ch),  T=32, +bias
__global__ __launch_bounds__(256, 2)
void ce_all_k(const unsigned short* __restrict__ h1, const unsigned short* __restrict__ t1w2,
              const int* __restrict__ n1p, float* __restrict__ ps1,
              const unsigned short* __restrict__ h0, const unsigned short* __restrict__ t0w2,
              const int* __restrict__ n0p, float* __restrict__ ps0,
              const unsigned short* __restrict__ win, const unsigned short* __restrict__ hw,
              const float* __restrict__ head_b, float* __restrict__ psh) {
    __shared__ unsigned short Asm[3 * ASTG];
    __shared__ unsigned short Bsm[3 * BSTG];
    __shared__ float cs[256][2];
    int bid = blockIdx.x;
    const unsigned short* A; const unsigned short* B; const float* bias = nullptr;
    int n, V, kbits, T, rb, ch;
    float* ps;
    if (bid < 5008) {
        rb = bid / 313; ch = bid % 313;
        A = h1; B = t1w2; n = *n1p; V = 40000; kbits = 8; T = 8;
        ps = ps1;
    } else if (bid < 6016) {
        int b = bid - 5008; rb = b / 63; ch = b % 63;
        A = h0; B = t0w2; n = *n0p; V = 8000; kbits = 10; T = 32;
        ps = ps0;
    } else {
        int b = bid - 6016; rb = b >> 4; ch = b & 15;
        A = win; B = hw; n = NTOK; V = 2002; kbits = 10; T = 32;
        ps = psh; bias = head_b;
    }
    int row_base = rb * 256;
    if (row_base >= n) return;
    int colb = ch << 7;
    int Vm1 = V - 1;
    int t = threadIdx.x;
    int wave = t >> 6, lane = t & 63;
    int wrow = (wave >> 1) * 128, wcol = (wave & 1) * 64;
    int fr = lane & 15, fk = lane >> 4;

    // staging: A 256x32 (4 instr/wave, 16-row steps), B 128x32 (2 instr/wave)
    int sra = wave * 64 + (lane >> 2);
    int srb = wave * 32 + (lane >> 2);
    int c0l = lane & 3;
    int gca = c0l ^ ((sra >> 1) & 3);   // +16 row steps preserve (r>>1)&3
    int gcb = c0l ^ ((srb >> 1) & 3);
    const unsigned short* Ap0 = A + (((size_t)(row_base + sra)) << kbits) + gca * 8;
    const unsigned short* Ap1 = A + (((size_t)(row_base + sra + 16)) << kbits) + gca * 8;
    const unsigned short* Ap2 = A + (((size_t)(row_base + sra + 32)) << kbits) + gca * 8;
    const unsigned short* Ap3 = A + (((size_t)(row_base + sra + 48)) << kbits) + gca * 8;
    int br0 = colb + srb;      if (br0 > Vm1) br0 = Vm1;
    int br1 = colb + srb + 16; if (br1 > Vm1) br1 = Vm1;
    const unsigned short* Bp0 = B + (((size_t)br0) << kbits) + gcb * 8;
    const unsigned short* Bp1 = B + (((size_t)br1) << kbits) + gcb * 8;

    auto issue = [&](int s, int slot) {
        int koff = s << 5;
        unsigned short* as = Asm + slot * ASTG + wave * 2048;
        unsigned short* bs = Bsm + slot * BSTG + wave * 1024;
        gload16(Ap0 + koff, as);        gload16(Ap1 + koff, as + 512);
        gload16(Ap2 + koff, as + 1024); gload16(Ap3 + koff, as + 1536);
        gload16(Bp0 + koff, bs);        gload16(Bp1 + koff, bs + 512);
    };

    int sw = (fk ^ ((fr >> 1) & 3)) * 8;
    int ra[8], rc[4];
#pragma unroll
    for (int i = 0; i < 8; ++i) ra[i] = (wrow + i * 16 + fr) * 32 + sw;
#pragma unroll
    for (int i = 0; i < 4; ++i) rc[i] = (wcol + i * 16 + fr) * 32 + sw;

    issue(0, 0); issue(1, 1);
    floatx4 acc[8][4] = {};
    int sc = 0, si = 2;
    for (int j = 0; j < T; ++j) {
        if (j + 2 < T) { issue(j + 2, si); si = (si == 2) ? 0 : si + 1; }
        int rem = T - 1 - j;
        if (rem >= 2) { WAIT_VM12(); }
        else if (rem == 1) { WAIT_VM6(); }
        else { WAIT_VM0(); }
        WAIT_LGKM();
        __builtin_amdgcn_s_barrier();
        const unsigned short* As = Asm + sc * ASTG;
        const unsigned short* Bs = Bsm + sc * BSTG;
        sc = (sc == 2) ? 0 : sc + 1;
        short8 af[8], bf[4];
#pragma unroll
        for (int i = 0; i < 8; ++i) af[i] = *(const short8*)&As[ra[i]];
#pragma unroll
        for (int i = 0; i < 4; ++i) bf[i] = *(const short8*)&Bs[rc[i]];
#pragma unroll
        for (int rt = 0; rt < 8; ++rt)
#pragma unroll
            for (int ct = 0; ct < 4; ++ct)
                acc[rt][ct] = __builtin_amdgcn_mfma_f32_16x16x32_bf16(af[rt], bf[ct], acc[rt][ct], 0, 0, 0);
    }

    // epilogue: per-row sum of exp(acc)*ebv. |logit| < ~6 (xavier) -> max-free
    // sum(exp) is fp32-safe. OOB columns: ebv=0 kills them (exp(acc) is finite).
    float ebv[4];
#pragma unroll
    for (int ct = 0; ct < 4; ++ct) {
        int vcol = colb + wcol + ct * 16 + fr;
        ebv[ct] = (vcol < V) ? ((bias != nullptr) ? __expf(bias[vcol]) : 1.0f) : 0.0f;
    }
#pragma unroll
    for (int rt = 0; rt < 8; ++rt) {
#pragma unroll
        for (int r = 0; r < 4; ++r) {
            float s = 0.f;
#pragma unroll
            for (int ct = 0; ct < 4; ++ct)
                s = fmaf(__expf(acc[rt][ct][r]), ebv[ct], s);
            s = row16_sum(s);
            if (fr == 0) cs[wrow + rt * 16 + fk * 4 + r][wave & 1] = s;
        }
    }
    __syncthreads();
    ps[(size_t)ch * NTOK + row_base + t] = cs[t][0] + cs[t][1];
}

// ---------------- reduce: wave-per-token LSE + label-logit dot + NLL ----------------
// One wave per token (12288 waves / 3072 blocks -- round-2 bug was launching
// 48 blocks). 64-lane-parallel partial sums + bf16 K-dot for the label logit.
__global__ __launch_bounds__(256)
void reduce_all_k(const float* __restrict__ ps0, const unsigned short* __restrict__ h0,
                  const unsigned short* __restrict__ t0w2, const int* __restrict__ lab0,
                  const int* __restrict__ n0p,
                  const float* __restrict__ ps1, const unsigned short* __restrict__ h1,
                  const unsigned short* __restrict__ t1w2, const int* __restrict__ lab1,
                  const int* __restrict__ n1p,
                  const float* __restrict__ psh, const unsigned short* __restrict__ win,
                  const unsigned short* __restrict__ hw, const int* __restrict__ labh,
                  const float* __restrict__ head_b,
                  float* __restrict__ lossb) {
    __shared__ float part[4];
    int tid = threadIdx.x, lane = tid & 63, w = tid >> 6;
    int wid = blockIdx.x * 4 + w;
    int seg = wid >> 12, p = wid & 4095;
    const float* ps; const unsigned short* A; const unsigned short* B; const int* lab;
    int n, nc, kbits;
    if (seg == 0)      { ps = ps0; A = h0;  B = t0w2; lab = lab0; n = *n0p; nc = 63;  kbits = 10; }
    else if (seg == 1) { ps = ps1; A = h1;  B = t1w2; lab = lab1; n = *n1p; nc = 313; kbits = 8; }
    else               { ps = psh; A = win; B = hw;   lab = labh; n = NTOK; nc = 16;  kbits = 10; }
    float nll = 0.f;
    if (p < n) {                       // wave-uniform (p is per-wave)
        int L = lab[p];
        float S = 0.f;
        for (int c = lane; c < nc; c += 64) S += ps[(size_t)c * NTOK + p];
        int K = 1 << kbits;
        const unsigned short* ar = A + ((size_t)p << kbits);
        const unsigned short* br = B + ((size_t)L << kbits);
        float d = 0.f;
        for (int k = lane * 8; k < K; k += 512) {
            short8 av = *(const short8*)(ar + k);
            short8 bv = *(const short8*)(br + k);
#pragma unroll
            for (int e = 0; e < 8; ++e)
                d = fmaf(bf2f((unsigned short)av[e]), bf2f((unsigned short)bv[e]), d);
        }
#pragma unroll
        for (int off = 1; off < 64; off <<= 1) {
            S += __shfl_xor(S, off, 64);
            d += __shfl_xor(d, off, 64);
        }
        if (lane == 0) {
            float bias = (seg == 2) ? head_b[L] : 0.f;
            nll = logf(S) - d - bias;
        }
    }
    if (lane == 0) part[w] = nll;
    __syncthreads();
    if (tid == 0) atomicAdd(&lossb[blockIdx.x & 63], part[0] + part[1] + part[2] + part[3]);
}

__global__ void final_k(const float* __restrict__ lossb, float* __restrict__ out) {
    float v = lossb[threadIdx.x];
    for (int off = 32; off; off >>= 1) v += __shfl_down(v, off, 64);
    if (threadIdx.x == 0) out[0] = v * (1.0f / 4096.0f);
}

extern "C" void kernel_launch(void* const* d_in, const int* in_sizes, int n_in,
                              void* d_out, int out_size, void* d_ws, size_t ws_size,
                              hipStream_t stream) {
    const float* w_in   = (const float*)d_in[0];
    const int*   target = (const int*)d_in[1];
    const float* head_w = (const float*)d_in[2];
    const float* head_b = (const float*)d_in[3];
    const float* t0w1   = (const float*)d_in[4];
    const float* t0w2   = (const float*)d_in[5];
    const float* t1w1   = (const float*)d_in[6];
    const float* t1w2   = (const float*)d_in[7];
    float* out = (float*)d_out;

    char* wsb = (char*)d_ws;
    size_t o = 0;
    auto alloc = [&](size_t bytes) -> void* {
        void* p = wsb + o;
        o += (bytes + 255) & ~(size_t)255;
        return p;
    };
    float* lossb = (float*)alloc(64 * 4);   // 64 partial-loss buckets (offset 0)
    int* n0 = (int*)alloc(4);               // offset 256
    int* n1 = (int*)alloc(4);               // offset 512
    int* idx0 = (int*)alloc(NTOK * 4);
    int* lab0 = (int*)alloc(NTOK * 4);
    int* idx1 = (int*)alloc(NTOK * 4);
    int* lab1 = (int*)alloc(NTOK * 4);
    int* labh = (int*)alloc(NTOK * 4);

    const int SZ_WIN = NTOK * 1024, SZ_HW = 2002 * 1024, SZ_T0W1 = 1024 * 1024,
              SZ_T0W2 = 8000 * 1024, SZ_T1W1 = 256 * 1024, SZ_T1W2 = 40000 * 256;
    unsigned short* win_bf  = (unsigned short*)alloc((size_t)SZ_WIN * 2);
    unsigned short* hw_bf   = (unsigned short*)alloc((size_t)SZ_HW * 2);
    unsigned short* t0w1_bf = (unsigned short*)alloc((size_t)SZ_T0W1 * 2);
    unsigned short* t0w2_bf = (unsigned short*)alloc((size_t)SZ_T0W2 * 2);
    unsigned short* t1w1_bf = (unsigned short*)alloc((size_t)SZ_T1W1 * 2);
    unsigned short* t1w2_bf = (unsigned short*)alloc((size_t)SZ_T1W2 * 2);
    unsigned short* h0 = (unsigned short*)alloc((size_t)NTOK * 1024 * 2);
    unsigned short* h1 = (unsigned short*)alloc((size_t)NTOK * 256 * 2);

    const int NC0 = 63, NC1 = 313, NCH = 16;   // chunks per segment (per-chunk partials)
    float* ps0 = (float*)alloc((size_t)NC0 * NTOK * 4);
    float* ps1 = (float*)alloc((size_t)NC1 * NTOK * 4);
    float* psh = (float*)alloc((size_t)NCH * NTOK * 4);

    dim3 blk(256);
    hipMemsetAsync(d_ws, 0, 768, stream);   // zero lossb, n0, n1

    // prep: compact (16 blocks) + cvt of win/t0w1/t1w1 (1376 blocks)
    prep_k<<<16 + 1376, blk, 0, stream>>>(
        w_in, win_bf, t0w1, t0w1_bf, t1w1, t1w1_bf,
        target, idx0, lab0, n0, idx1, lab1, n1, labh);

    // hgemm (320 blocks, ~100 active) overlapped with cvt of hw/t0w2/t1w2 (1280 blocks)
    hgemm_cvt_k<<<320 + 1280, blk, 0, stream>>>(
        win_bf, t0w1_bf, h0, idx0, n0, t1w1_bf, h1, idx1, n1,
        head_w, hw_bf, t0w2, t0w2_bf, t1w2, t1w2_bf);

    ce_all_k<<<5008 + 1008 + 256, blk, 0, stream>>>(
        h1, t1w2_bf, n1, ps1,
        h0, t0w2_bf, n0, ps0,
        win_bf, hw_bf, head_b, psh);

    // one wave per token: 3*4096 waves, 4 waves/block -> 3072 blocks
    reduce_all_k<<<3 * NTOK / 4, blk, 0, stream>>>(
        ps0, h0, t0w2_bf, lab0, n0,
        ps1, h1, t1w2_bf, lab1, n1,
        psh, win_bf, hw_bf, labh, head_b, lossb);

    final_k<<<1, 64, 0, stream>>>(lossb, out);
}